// Round 4
// baseline (291.633 us; speedup 1.0000x reference)
//
#include <hip/hip_runtime.h>
#include <math.h>

#define HH 512
#define WW 512
#define IMG (HH*WW)
#define NIMG_PER 96   // B*C = 32*3
#define NIMG 192      // pred + targ
#define NBIN 256      // max_r
#define EPSV 1e-8f

#define IMGC (257*512)         // float2 per image; layout [kx][y], kx=0..256
#define SLOT 576               // padded per-FFT LDS stride; fsw(511)=574 < 576

// octal-digit reversal of 9-bit index (3 radix-8 stages)
__device__ __forceinline__ int drev(int s) {
    return ((s & 7) << 6) | (s & 56) | (s >> 6);
}
// bank swizzle: keeps every FFT access pattern <=2-way on 32 banks
__device__ __forceinline__ int fsw(int a) { return a + (a >> 3); }

__device__ __forceinline__ float2 cmul(float2 a, float2 b) {
    return make_float2(a.x*b.x - a.y*b.y, a.x*b.y + a.y*b.x);
}
#define C_ADD(a,b) make_float2((a).x+(b).x, (a).y+(b).y)
#define C_SUB(a,b) make_float2((a).x-(b).x, (a).y-(b).y)
#define C_NI(a)    make_float2((a).y, -(a).x)   // * (-i)

// radix-8 DIF butterfly, negative exponent
__device__ __forceinline__ void bfly8(float2 x[8]) {
    const float R = 0.70710678118654752440f;
    float2 t0=C_ADD(x[0],x[4]), t4=C_SUB(x[0],x[4]);
    float2 t1=C_ADD(x[1],x[5]), t5=C_SUB(x[1],x[5]);
    float2 t2=C_ADD(x[2],x[6]), t6=C_SUB(x[2],x[6]);
    float2 t3=C_ADD(x[3],x[7]), t7=C_SUB(x[3],x[7]);
    float2 u0=C_ADD(t0,t2), u2=C_SUB(t0,t2);
    float2 u1=C_ADD(t1,t3), u3=C_SUB(t1,t3);
    x[0]=C_ADD(u0,u1); x[4]=C_SUB(u0,u1);
    { float2 n3 = C_NI(u3); x[2]=C_ADD(u2,n3); x[6]=C_SUB(u2,n3); }
    float2 s1 = make_float2(R*(t5.x + t5.y), R*(t5.y - t5.x));   // * (R - iR)
    float2 s2 = C_NI(t6);
    float2 s3 = make_float2(R*(t7.y - t7.x), -R*(t7.x + t7.y));  // * (-R - iR)
    float2 v0=C_ADD(t4,s2), v2=C_SUB(t4,s2);
    float2 v1=C_ADD(s1,s3), v3=C_SUB(s1,s3);
    x[1]=C_ADD(v0,v1); x[5]=C_SUB(v0,v1);
    { float2 n3 = C_NI(v3); x[3]=C_ADD(v2,n3); x[7]=C_SUB(v2,n3); }
}

// x[j] *= w^j, w = exp(i*ang); chain depth 3 for ILP
__device__ __forceinline__ void twiddle7(float2* x, float ang) {
    const float sn = __sinf(ang), cs = __cosf(ang);
    const float2 w1 = make_float2(cs, sn);
    const float2 w2 = cmul(w1, w1);
    const float2 w3 = cmul(w2, w1);
    const float2 w4 = cmul(w2, w2);
    const float2 w5 = cmul(w2, w3);
    const float2 w6 = cmul(w3, w3);
    const float2 w7 = cmul(w3, w4);
    x[1]=cmul(x[1],w1); x[2]=cmul(x[2],w2); x[3]=cmul(x[3],w3);
    x[4]=cmul(x[4],w4); x[5]=cmul(x[5],w5); x[6]=cmul(x[6],w6);
    x[7]=cmul(x[7],w7);
}

// ---------------------------------------------------------------------------
// Pass A: one block per 4 row-pairs (8 image rows). Pack rows (2p,2p+1) as
// a+ib, radix-8 512-pt DIF FFT, Hermitian unpack, write TRANSPOSED [kx][y]
// directly to global (scattered 16B stores; no LDS plane phase).
// ---------------------------------------------------------------------------
__global__ __launch_bounds__(256) void rowfft_kernel(
    const float* __restrict__ pred, const float* __restrict__ targ,
    float2* __restrict__ out, int img_base)
{
    __shared__ float sre[4*SLOT], sim[4*SLOT];
    const int t = threadIdx.x;

    const int pb = blockIdx.x;          // rows pb*8 .. pb*8+7
    const int li = blockIdx.y;
    const int g  = img_base + li;
    const float* img = (g < NIMG_PER) ? (pred + (size_t)g * IMG)
                                      : (targ + (size_t)(g - NIMG_PER) * IMG);
    const float4* src4 = (const float4*)(img + (size_t)(pb*8) * WW);

    #pragma unroll
    for (int it = 0; it < 4; ++it) {
        const int id = it*256 + t;      // r*128 + x4
        const int r  = id >> 7;
        const int x4 = id & 127;
        const float4 v = src4[id];
        float* dst = ((r & 1) ? sim : sre) + (r >> 1) * SLOT;
        const int b = 4*x4 + (x4 >> 1); // = fsw(4*x4)
        dst[b+0]=v.x; dst[b+1]=v.y; dst[b+2]=v.z; dst[b+3]=v.w;
    }
    __syncthreads();

    const int i    = t & 63;
    const int slot = t >> 6;
    float* re = sre + slot*SLOT;
    float* im = sim + slot*SLOT;
    float2 x[8];

    // ---- stage 1: stride 64, twiddle w512^(i*j)
    #pragma unroll
    for (int j = 0; j < 8; ++j) { int a = fsw(i + 64*j); x[j] = make_float2(re[a], im[a]); }
    bfly8(x);
    twiddle7(x, -0.012271846303085130f * (float)i);       // -2pi/512 * i
    #pragma unroll
    for (int j = 0; j < 8; ++j) { int a = fsw(i + 64*j); re[a] = x[j].x; im[a] = x[j].y; }
    __syncthreads();

    // ---- stage 2: groups of 64, twiddle w64^(i2*j)
    const int grp = i >> 3, i2 = i & 7;
    #pragma unroll
    for (int j = 0; j < 8; ++j) { int a = fsw(64*grp + i2 + 8*j); x[j] = make_float2(re[a], im[a]); }
    bfly8(x);
    twiddle7(x, -0.098174770424681038f * (float)i2);      // -2pi/64 * i2
    #pragma unroll
    for (int j = 0; j < 8; ++j) { int a = fsw(64*grp + i2 + 8*j); re[a] = x[j].x; im[a] = x[j].y; }
    __syncthreads();

    // ---- stage 3: contiguous 8, no twiddle
    #pragma unroll
    for (int j = 0; j < 8; ++j) { int a = fsw(8*i + j); x[j] = make_float2(re[a], im[a]); }
    bfly8(x);
    #pragma unroll
    for (int j = 0; j < 8; ++j) { int a = fsw(8*i + j); re[a] = x[j].x; im[a] = x[j].y; }
    __syncthreads();

    // ---- Hermitian unpack -> transposed global write.
    // Wave w in {1,2,3}: k = drev(t) covers residues {w, 8-w}; wave 0 lanes
    // 0..31: k=8d+4 (residue 4), lanes 32..63: k=8d (residue 0, incl. k=0
    // self-pair at t=32, which the general formula handles since a2==a1).
    const int w_ = t >> 6;
    const int k  = (w_ > 0) ? (((t & 7) << 6) | (t & 56) | w_)
                            : ((t < 32) ? (8*t + 4) : (8*(t - 32)));
    const int kk = (k <= 256) ? k : (512 - k);
    const int a1 = fsw(drev(kk));
    const int a2 = fsw(drev((512 - kk) & 511));

    float4* dst = (float4*)out + (size_t)li * (IMGC/2) + (size_t)kk * 256 + pb*4;
    #pragma unroll
    for (int s = 0; s < 4; ++s) {
        const float Pr = sre[s*SLOT + a1], Pi = sim[s*SLOT + a1];
        const float Qr = sre[s*SLOT + a2], Qi = sim[s*SLOT + a2];
        // (Fa.x, Fa.y, Fb.x, Fb.y) for rows (2s, 2s+1) of this block
        dst[s] = make_float4(0.5f*(Pr+Qr), 0.5f*(Pi-Qi),
                             0.5f*(Pi+Qi), 0.5f*(Qr-Pr));
    }
    if (t == 0) {                       // column kx=256 from Z(256) (real pair)
        const int a3 = fsw(drev(256));
        float4* d2 = (float4*)out + (size_t)li * (IMGC/2) + (size_t)256 * 256 + pb*4;
        #pragma unroll
        for (int s = 0; s < 4; ++s)
            d2[s] = make_float4(sre[s*SLOT + a3], 0.0f, sim[s*SLOT + a3], 0.0f);
    }
}

// ---------------------------------------------------------------------------
// Pass B: one block per (image, 4-column tile). Coalesced [kx][y] reads,
// 4 radix-8 column FFTs (1 per wave-slot), PSD+log+radial bin from registers.
// ---------------------------------------------------------------------------
__global__ __launch_bounds__(256) void colfft_kernel(
    const float2* __restrict__ in, float* __restrict__ bins, int img_base)
{
    __shared__ float sre[4*SLOT], sim[4*SLOT];
    __shared__ float bsum[NBIN];
    const int t = threadIdx.x;
    bsum[t] = 0.0f;

    const int li = blockIdx.y;
    const int x0 = blockIdx.x * 4;
    const float2* src = in + (size_t)li * IMGC;

    #pragma unroll
    for (int it = 0; it < 8; ++it) {
        const int cl = it >> 1;           // column slot (uniform per iter)
        const int kx = x0 + cl;
        const int y  = ((it & 1) << 8) + t;
        float2 v = make_float2(0.0f, 0.0f);
        if (kx <= 256) v = src[(size_t)kx * 512 + y];   // fully coalesced
        const int a = cl*SLOT + fsw(y);
        sre[a] = v.x; sim[a] = v.y;
    }
    __syncthreads();

    const int i  = t & 63;
    const int c0 = t >> 6;
    float* re = sre + c0*SLOT;
    float* im = sim + c0*SLOT;
    float2 x[8];

    // ---- stage 1
    #pragma unroll
    for (int j = 0; j < 8; ++j) { int a = fsw(i + 64*j); x[j] = make_float2(re[a], im[a]); }
    bfly8(x);
    twiddle7(x, -0.012271846303085130f * (float)i);
    #pragma unroll
    for (int j = 0; j < 8; ++j) { int a = fsw(i + 64*j); re[a] = x[j].x; im[a] = x[j].y; }
    __syncthreads();

    // ---- stage 2
    const int grp = i >> 3, i2 = i & 7;
    #pragma unroll
    for (int j = 0; j < 8; ++j) { int a = fsw(64*grp + i2 + 8*j); x[j] = make_float2(re[a], im[a]); }
    bfly8(x);
    twiddle7(x, -0.098174770424681038f * (float)i2);
    #pragma unroll
    for (int j = 0; j < 8; ++j) { int a = fsw(64*grp + i2 + 8*j); re[a] = x[j].x; im[a] = x[j].y; }
    __syncthreads();

    // ---- stage 3 + PSD + radial bin straight from registers
    {
        const int kx = x0 + c0;
        #pragma unroll
        for (int j = 0; j < 8; ++j) { int a = fsw(8*i + j); x[j] = make_float2(re[a], im[a]); }
        bfly8(x);
        if (kx <= 256) {
            const float wgt = (kx == 0 || kx == 256) ? 1.0f : 2.0f;
            const int dx = kx - 256;
            #pragma unroll
            for (int j = 0; j < 8; ++j) {
                const int q  = 8*i + j;           // storage row -> ky = drev(q)
                const int ky = drev(q);
                const float val = __logf(x[j].x*x[j].x + x[j].y*x[j].y + EPSV);
                const int dy = ky - 256;
                const int b  = (int)sqrtf((float)(dy*dy + dx*dx));
                if (b < NBIN) atomicAdd(&bsum[b], wgt * val);
            }
        }
    }
    __syncthreads();

    atomicAdd(&bins[(size_t)(img_base + li) * NBIN + t], bsum[t]);
}

// ---------------------------------------------------------------------------
// Bin counts over the full 512x512 grid (image-independent).
// ---------------------------------------------------------------------------
__global__ __launch_bounds__(256) void counts_kernel(float* __restrict__ cnt)
{
    __shared__ float c[NBIN];
    const int t = threadIdx.x;
    c[t] = 0.0f;
    __syncthreads();

    const int base = blockIdx.x * 4096;
    #pragma unroll
    for (int i = 0; i < 16; ++i) {
        const int id = base + i * 256 + t;
        const int y = id >> 9, xx = id & 511;
        const int dy = y - 256, dx = xx - 256;
        const int b  = (int)sqrtf((float)(dy*dy + dx*dx));
        if (b < NBIN) atomicAdd(&c[b], 1.0f);
    }
    __syncthreads();
    if (c[t] != 0.0f) atomicAdd(&cnt[t], c[t]);
}

// ---------------------------------------------------------------------------
// Finalize: mean over (pair, bin) of |sum_p - sum_t| / cnt.
// ---------------------------------------------------------------------------
__global__ __launch_bounds__(256) void finalize_kernel(
    const float* __restrict__ bins, const float* __restrict__ cnt,
    float* __restrict__ out)
{
    __shared__ float red[256];
    const int t = threadIdx.x;

    float acc = 0.0f;
    for (int id = t; id < NIMG_PER * NBIN; id += 256) {
        const int i = id >> 8;
        const int r = id & 255;
        const float d = fabsf(bins[(size_t)i * NBIN + r]
                            - bins[(size_t)(NIMG_PER + i) * NBIN + r]);
        acc += d / cnt[r];
    }
    red[t] = acc;
    __syncthreads();
    for (int w = 128; w > 0; w >>= 1) {
        if (t < w) red[t] += red[t + w];
        __syncthreads();
    }
    if (t == 0) out[0] = red[0] / (float)(NIMG_PER * NBIN);
}

// ---------------------------------------------------------------------------
extern "C" void kernel_launch(void* const* d_in, const int* in_sizes, int n_in,
                              void* d_out, int out_size, void* d_ws, size_t ws_size,
                              hipStream_t stream)
{
    const float* pred = (const float*)d_in[0];
    const float* targ = (const float*)d_in[1];
    float* out = (float*)d_out;

    char* ws = (char*)d_ws;
    float* bins = (float*)ws;                        // NIMG*NBIN accumulators
    float* cnt  = bins + (size_t)NIMG * NBIN;        // NBIN counts
    const size_t zero_bytes = ((size_t)NIMG * NBIN + NBIN) * sizeof(float);
    const size_t off = (zero_bytes + 255) & ~(size_t)255;
    float2* cbuf = (float2*)(ws + off);

    const size_t per_img = (size_t)IMGC * sizeof(float2);   // ~1.05 MiB
    size_t avail = (ws_size > off) ? (ws_size - off) : 0;
    int chunk = (int)(avail / per_img);
    if (chunk > NIMG) chunk = NIMG;
    if (chunk < 1) chunk = 1;

    hipMemsetAsync(bins, 0, zero_bytes, stream);
    counts_kernel<<<dim3(64), dim3(256), 0, stream>>>(cnt);

    for (int base = 0; base < NIMG; base += chunk) {
        const int n = (NIMG - base < chunk) ? (NIMG - base) : chunk;
        dim3 gA(HH / 8, n), gB(65, n), blk(256);
        rowfft_kernel<<<gA, blk, 0, stream>>>(pred, targ, cbuf, base);
        colfft_kernel<<<gB, blk, 0, stream>>>(cbuf, bins, base);
    }

    finalize_kernel<<<dim3(1), dim3(256), 0, stream>>>(bins, cnt, out);
}

// Round 5
// 259.412 us; speedup vs baseline: 1.1242x; 1.1242x over previous
//
#include <hip/hip_runtime.h>
#include <math.h>

#define HH 512
#define WW 512
#define IMG (HH*WW)
#define NIMG_PER 96   // B*C = 32*3
#define NIMG 192      // pred + targ
#define NBIN 256      // max_r
#define EPSV 1e-8f

#define CSTR 264               // padded column count (257 used + 7 zero pad)
#define IMGC (512*CSTR)        // float2 elements per image in cbuf [y][kx]
#define SLOT 580               // per-FFT LDS stride in float2; fsw(511)=574<580

// octal-digit reversal of 9-bit index (3 radix-8 stages)
__device__ __forceinline__ int drev(int s) {
    return ((s & 7) << 6) | (s & 56) | (s >> 6);
}
// bank swizzle on float2 element index: every stage pattern <=4-way/bank-pair
__device__ __forceinline__ int fsw(int a) { return a + (a >> 3); }

__device__ __forceinline__ float2 cmul(float2 a, float2 b) {
    return make_float2(a.x*b.x - a.y*b.y, a.x*b.y + a.y*b.x);
}
#define C_ADD(a,b) make_float2((a).x+(b).x, (a).y+(b).y)
#define C_SUB(a,b) make_float2((a).x-(b).x, (a).y-(b).y)
#define C_NI(a)    make_float2((a).y, -(a).x)   // * (-i)

// radix-8 DIF butterfly, negative exponent
__device__ __forceinline__ void bfly8(float2 x[8]) {
    const float R = 0.70710678118654752440f;
    float2 t0=C_ADD(x[0],x[4]), t4=C_SUB(x[0],x[4]);
    float2 t1=C_ADD(x[1],x[5]), t5=C_SUB(x[1],x[5]);
    float2 t2=C_ADD(x[2],x[6]), t6=C_SUB(x[2],x[6]);
    float2 t3=C_ADD(x[3],x[7]), t7=C_SUB(x[3],x[7]);
    float2 u0=C_ADD(t0,t2), u2=C_SUB(t0,t2);
    float2 u1=C_ADD(t1,t3), u3=C_SUB(t1,t3);
    x[0]=C_ADD(u0,u1); x[4]=C_SUB(u0,u1);
    { float2 n3 = C_NI(u3); x[2]=C_ADD(u2,n3); x[6]=C_SUB(u2,n3); }
    float2 s1 = make_float2(R*(t5.x + t5.y), R*(t5.y - t5.x));   // * (R - iR)
    float2 s2 = C_NI(t6);
    float2 s3 = make_float2(R*(t7.y - t7.x), -R*(t7.x + t7.y));  // * (-R - iR)
    float2 v0=C_ADD(t4,s2), v2=C_SUB(t4,s2);
    float2 v1=C_ADD(s1,s3), v3=C_SUB(s1,s3);
    x[1]=C_ADD(v0,v1); x[5]=C_SUB(v0,v1);
    { float2 n3 = C_NI(v3); x[3]=C_ADD(v2,n3); x[7]=C_SUB(v2,n3); }
}

// x[j] *= w^j, w = exp(i*ang); chain depth 3 for ILP
__device__ __forceinline__ void twiddle7(float2* x, float ang) {
    const float sn = __sinf(ang), cs = __cosf(ang);
    const float2 w1 = make_float2(cs, sn);
    const float2 w2 = cmul(w1, w1);
    const float2 w3 = cmul(w2, w1);
    const float2 w4 = cmul(w2, w2);
    const float2 w5 = cmul(w2, w3);
    const float2 w6 = cmul(w3, w3);
    const float2 w7 = cmul(w3, w4);
    x[1]=cmul(x[1],w1); x[2]=cmul(x[2],w2); x[3]=cmul(x[3],w3);
    x[4]=cmul(x[4],w4); x[5]=cmul(x[5],w5); x[6]=cmul(x[6],w6);
    x[7]=cmul(x[7],w7);
}

// ---------------------------------------------------------------------------
// Pass A: one block per 4 row-pairs (8 image rows). Pack rows (2s,2s+1) as
// a+ib (float2 LDS), radix-8 512-pt DIF FFT, Hermitian unpack, LDS plane
// transpose, coalesced [y][kx] global writes.
// ---------------------------------------------------------------------------
__global__ __launch_bounds__(256) void rowfft_kernel(
    const float* __restrict__ pred, const float* __restrict__ targ,
    float2* __restrict__ out, int img_base)
{
    __shared__ float2 sd[2320];        // 4*580 FFT slots; reused as 8*290 planes
    const int t = threadIdx.x;

    const int pb = blockIdx.x;         // rows pb*8 .. pb*8+7
    const int li = blockIdx.y;
    const int g  = img_base + li;
    const float* img = (g < NIMG_PER) ? (pred + (size_t)g * IMG)
                                      : (targ + (size_t)(g - NIMG_PER) * IMG);
    const float4* src4 = (const float4*)(img + (size_t)(pb*8) * WW);

    // load: slot s packs rows (2s, 2s+1) as (re, im)
    #pragma unroll
    for (int it = 0; it < 2; ++it) {
        const int id = it*256 + t;     // 0..511 = s*128 + x4
        const int s  = id >> 7;
        const int x4 = id & 127;
        const float4 va = src4[(2*s)   * 128 + x4];
        const float4 vb = src4[(2*s+1) * 128 + x4];
        float2* p = sd + s*SLOT + (4*x4 + (x4 >> 1));   // fsw(4*x4), +0..3 stay in run
        p[0] = make_float2(va.x, vb.x);
        p[1] = make_float2(va.y, vb.y);
        p[2] = make_float2(va.z, vb.z);
        p[3] = make_float2(va.w, vb.w);
    }
    __syncthreads();

    const int i = t & 63;
    float2* p = sd + (t >> 6) * SLOT;
    float2 x[8];

    // stage 1: stride 64
    #pragma unroll
    for (int j = 0; j < 8; ++j) x[j] = p[fsw(i + 64*j)];
    bfly8(x);
    twiddle7(x, -0.012271846303085130f * (float)i);       // -2pi/512 * i
    #pragma unroll
    for (int j = 0; j < 8; ++j) p[fsw(i + 64*j)] = x[j];
    __syncthreads();

    // stage 2: groups of 64
    const int grp = i >> 3, i2 = i & 7;
    #pragma unroll
    for (int j = 0; j < 8; ++j) x[j] = p[fsw(64*grp + i2 + 8*j)];
    bfly8(x);
    twiddle7(x, -0.098174770424681038f * (float)i2);      // -2pi/64 * i2
    #pragma unroll
    for (int j = 0; j < 8; ++j) p[fsw(64*grp + i2 + 8*j)] = x[j];
    __syncthreads();

    // stage 3: contiguous 8
    #pragma unroll
    for (int j = 0; j < 8; ++j) x[j] = p[fsw(8*i + j)];
    bfly8(x);
    #pragma unroll
    for (int j = 0; j < 8; ++j) p[fsw(8*i + j)] = x[j];
    __syncthreads();

    // Hermitian unpack: wave w in {1,2,3}: k=drev(t) covers residues {w,8-w};
    // wave 0 lanes 0..31: k=8t+4, lanes 32..63: k=8(t-32) (t=32 -> k=0
    // self-pair, handled by the general formula since a2==a1).
    const int w_ = t >> 6;
    const int k  = (w_ > 0) ? (((t & 7) << 6) | (t & 56) | w_)
                            : ((t < 32) ? (8*t + 4) : (8*(t - 32)));
    const int kk = (k <= 256) ? k : (512 - k);
    const int a1 = fsw(drev(kk));
    const int a2 = fsw(drev((512 - kk) & 511));
    const int a3 = fsw(drev(256));

    float2 A[4], Bv[4], Z[4];
    #pragma unroll
    for (int s = 0; s < 4; ++s) {
        const float2 P = sd[s*SLOT + a1];
        const float2 Q = sd[s*SLOT + a2];
        A[s]  = make_float2(0.5f*(P.x + Q.x), 0.5f*(P.y - Q.y));
        Bv[s] = make_float2(0.5f*(P.y + Q.y), 0.5f*(Q.x - P.x));
        Z[s]  = sd[s*SLOT + a3];        // Z(256): F_a(256)=Re, F_b(256)=Im
    }
    __syncthreads();

    // planes: plane r = 2s+h (h: 0=Fa row 2s, 1=Fb row 2s+1), stride 290
    {
        const int fb = fsw(kk);
        #pragma unroll
        for (int s = 0; s < 4; ++s) {
            sd[(2*s+0)*290 + fb] = A[s];
            sd[(2*s+1)*290 + fb] = Bv[s];
        }
    }
    if (t == 0) {
        const int fb = fsw(256);
        #pragma unroll
        for (int s = 0; s < 4; ++s) {
            sd[(2*s+0)*290 + fb] = make_float2(Z[s].x, 0.0f);
            sd[(2*s+1)*290 + fb] = make_float2(Z[s].y, 0.0f);
        }
    }
    __syncthreads();

    // coalesced copy planes -> global rows, zero pad cols 257..263
    float2* dst = out + (size_t)li * IMGC + (size_t)(pb*8) * CSTR;
    #pragma unroll
    for (int r = 0; r < 8; ++r) {
        dst[(size_t)r * CSTR + t] = sd[r*290 + fsw(t)];
        if (t < 8) {
            float2 v = make_float2(0.0f, 0.0f);
            if (t == 0) v = sd[r*290 + fsw(256)];
            dst[(size_t)r * CSTR + 256 + t] = v;
        }
    }
}

// ---------------------------------------------------------------------------
// Pass B: one block per (image, 8-column tile). 8 radix-8 column FFTs
// (2 per thread, shared twiddles), PSD+log+radial bin with 4-replica LDS
// accumulators (kills same-address atomic serialization).
// ---------------------------------------------------------------------------
__global__ __launch_bounds__(256) void colfft_kernel(
    const float2* __restrict__ in, float* __restrict__ bins, int img_base)
{
    __shared__ float2 sd[8*SLOT];
    __shared__ float  bs[4*257];
    const int t = threadIdx.x;
    #pragma unroll
    for (int id = t; id < 4*257; id += 256) bs[id] = 0.0f;

    const int li = blockIdx.y;
    const int x0 = blockIdx.x * 8;
    const float2* src = in + (size_t)li * IMGC;

    #pragma unroll
    for (int it = 0; it < 16; ++it) {
        const int id = it*256 + t;        // 0..4095
        const int y  = id >> 3;
        const int cl = id & 7;
        sd[cl*SLOT + fsw(y)] = src[(size_t)y * CSTR + (x0 + cl)];
    }
    __syncthreads();

    const int i  = t & 63;
    const int c0 = t >> 6;                // slots c0 and c0+4
    float2 x[2][8];

    // ---- stage 1
    #pragma unroll
    for (int sl = 0; sl < 2; ++sl) {
        float2* p = sd + (c0 + 4*sl)*SLOT;
        #pragma unroll
        for (int j = 0; j < 8; ++j) x[sl][j] = p[fsw(i + 64*j)];
        bfly8(x[sl]);
    }
    {
        const float ang = -0.012271846303085130f * (float)i;
        const float sn = __sinf(ang), cs = __cosf(ang);
        const float2 w1 = make_float2(cs, sn);
        const float2 w2 = cmul(w1,w1), w3 = cmul(w2,w1), w4 = cmul(w2,w2);
        const float2 w5 = cmul(w2,w3), w6 = cmul(w3,w3), w7 = cmul(w3,w4);
        #pragma unroll
        for (int sl = 0; sl < 2; ++sl) {
            x[sl][1]=cmul(x[sl][1],w1); x[sl][2]=cmul(x[sl][2],w2);
            x[sl][3]=cmul(x[sl][3],w3); x[sl][4]=cmul(x[sl][4],w4);
            x[sl][5]=cmul(x[sl][5],w5); x[sl][6]=cmul(x[sl][6],w6);
            x[sl][7]=cmul(x[sl][7],w7);
        }
    }
    #pragma unroll
    for (int sl = 0; sl < 2; ++sl) {
        float2* p = sd + (c0 + 4*sl)*SLOT;
        #pragma unroll
        for (int j = 0; j < 8; ++j) p[fsw(i + 64*j)] = x[sl][j];
    }
    __syncthreads();

    // ---- stage 2
    const int grp = i >> 3, i2 = i & 7;
    #pragma unroll
    for (int sl = 0; sl < 2; ++sl) {
        float2* p = sd + (c0 + 4*sl)*SLOT;
        #pragma unroll
        for (int j = 0; j < 8; ++j) x[sl][j] = p[fsw(64*grp + i2 + 8*j)];
        bfly8(x[sl]);
    }
    {
        const float ang = -0.098174770424681038f * (float)i2;
        const float sn = __sinf(ang), cs = __cosf(ang);
        const float2 w1 = make_float2(cs, sn);
        const float2 w2 = cmul(w1,w1), w3 = cmul(w2,w1), w4 = cmul(w2,w2);
        const float2 w5 = cmul(w2,w3), w6 = cmul(w3,w3), w7 = cmul(w3,w4);
        #pragma unroll
        for (int sl = 0; sl < 2; ++sl) {
            x[sl][1]=cmul(x[sl][1],w1); x[sl][2]=cmul(x[sl][2],w2);
            x[sl][3]=cmul(x[sl][3],w3); x[sl][4]=cmul(x[sl][4],w4);
            x[sl][5]=cmul(x[sl][5],w5); x[sl][6]=cmul(x[sl][6],w6);
            x[sl][7]=cmul(x[sl][7],w7);
        }
    }
    #pragma unroll
    for (int sl = 0; sl < 2; ++sl) {
        float2* p = sd + (c0 + 4*sl)*SLOT;
        #pragma unroll
        for (int j = 0; j < 8; ++j) p[fsw(64*grp + i2 + 8*j)] = x[sl][j];
    }
    __syncthreads();

    // ---- stage 3 + PSD + radial bin from registers.
    // Same-bin lanes are consecutive in c = 8*(i&7)+(i>>3); consecutive c
    // <=> consecutive (i>>3), so replica (i>>3)&3 spreads any collision run
    // across 4 accumulators (stride 257 keeps replicas on distinct banks).
    const int rep = ((i >> 3) & 3) * 257;
    #pragma unroll
    for (int sl = 0; sl < 2; ++sl) {
        const int cl = c0 + 4*sl;
        const int kx = x0 + cl;
        float2* p = sd + cl*SLOT;
        float2 y8[8];
        #pragma unroll
        for (int j = 0; j < 8; ++j) y8[j] = p[fsw(8*i + j)];
        bfly8(y8);
        if (kx <= 256) {
            const float wgt = (kx == 0 || kx == 256) ? 1.0f : 2.0f;
            const int dx = kx - 256;
            const int cbase = 8*(i & 7) + (i >> 3);
            #pragma unroll
            for (int j = 0; j < 8; ++j) {
                const int ky = 64*j + cbase;          // = drev(8i+j)
                const float val = __logf(y8[j].x*y8[j].x + y8[j].y*y8[j].y + EPSV);
                const int dy = ky - 256;
                const int b  = (int)sqrtf((float)(dy*dy + dx*dx));
                if (b < NBIN) atomicAdd(&bs[rep + b], wgt * val);
            }
        }
    }
    __syncthreads();

    const float v = bs[t] + bs[257 + t] + bs[514 + t] + bs[771 + t];
    atomicAdd(&bins[(size_t)(img_base + li) * NBIN + t], v);
}

// ---------------------------------------------------------------------------
// Bin counts over the full 512x512 grid (image-independent).
// ---------------------------------------------------------------------------
__global__ __launch_bounds__(256) void counts_kernel(float* __restrict__ cnt)
{
    __shared__ float c[NBIN];
    const int t = threadIdx.x;
    c[t] = 0.0f;
    __syncthreads();

    const int base = blockIdx.x * 4096;
    #pragma unroll
    for (int i = 0; i < 16; ++i) {
        const int id = base + i * 256 + t;
        const int y = id >> 9, xx = id & 511;
        const int dy = y - 256, dx = xx - 256;
        const int b  = (int)sqrtf((float)(dy*dy + dx*dx));
        if (b < NBIN) atomicAdd(&c[b], 1.0f);
    }
    __syncthreads();
    if (c[t] != 0.0f) atomicAdd(&cnt[t], c[t]);
}

// ---------------------------------------------------------------------------
// Finalize: mean over (pair, bin) of |sum_p - sum_t| / cnt.
// ---------------------------------------------------------------------------
__global__ __launch_bounds__(256) void finalize_kernel(
    const float* __restrict__ bins, const float* __restrict__ cnt,
    float* __restrict__ out)
{
    __shared__ float red[256];
    const int t = threadIdx.x;

    float acc = 0.0f;
    for (int id = t; id < NIMG_PER * NBIN; id += 256) {
        const int i = id >> 8;
        const int r = id & 255;
        const float d = fabsf(bins[(size_t)i * NBIN + r]
                            - bins[(size_t)(NIMG_PER + i) * NBIN + r]);
        acc += d / cnt[r];
    }
    red[t] = acc;
    __syncthreads();
    for (int w = 128; w > 0; w >>= 1) {
        if (t < w) red[t] += red[t + w];
        __syncthreads();
    }
    if (t == 0) out[0] = red[0] / (float)(NIMG_PER * NBIN);
}

// ---------------------------------------------------------------------------
extern "C" void kernel_launch(void* const* d_in, const int* in_sizes, int n_in,
                              void* d_out, int out_size, void* d_ws, size_t ws_size,
                              hipStream_t stream)
{
    const float* pred = (const float*)d_in[0];
    const float* targ = (const float*)d_in[1];
    float* out = (float*)d_out;

    char* ws = (char*)d_ws;
    float* bins = (float*)ws;                        // NIMG*NBIN accumulators
    float* cnt  = bins + (size_t)NIMG * NBIN;        // NBIN counts
    const size_t zero_bytes = ((size_t)NIMG * NBIN + NBIN) * sizeof(float);
    const size_t off = (zero_bytes + 255) & ~(size_t)255;
    float2* cbuf = (float2*)(ws + off);

    const size_t per_img = (size_t)IMGC * sizeof(float2);   // ~1.06 MiB
    size_t avail = (ws_size > off) ? (ws_size - off) : 0;
    int chunk = (int)(avail / per_img);
    if (chunk > NIMG) chunk = NIMG;
    if (chunk < 1) chunk = 1;

    hipMemsetAsync(bins, 0, zero_bytes, stream);
    counts_kernel<<<dim3(64), dim3(256), 0, stream>>>(cnt);

    for (int base = 0; base < NIMG; base += chunk) {
        const int n = (NIMG - base < chunk) ? (NIMG - base) : chunk;
        dim3 gA(HH / 8, n), gB(33, n), blk(256);
        rowfft_kernel<<<gA, blk, 0, stream>>>(pred, targ, cbuf, base);
        colfft_kernel<<<gB, blk, 0, stream>>>(cbuf, bins, base);
    }

    finalize_kernel<<<dim3(1), dim3(256), 0, stream>>>(bins, cnt, out);
}

// Round 6
// 238.665 us; speedup vs baseline: 1.2219x; 1.0869x over previous
//
#include <hip/hip_runtime.h>
#include <math.h>

#define HH 512
#define WW 512
#define IMG (HH*WW)
#define NIMG_PER 96   // B*C = 32*3
#define NIMG 192      // pred + targ
#define NBIN 256      // max_r
#define EPSV 1e-8f

#define CSTR 264               // padded column count (257 used + 7 zero pad)
#define IMGC (512*CSTR)        // float2 elements per image in cbuf [y][kx]
#define NTILE 33               // column tiles of 8 (kx 0..263)
#define SLOT 580               // per-FFT LDS stride in float2; fsw(511)=574<580

// octal-digit reversal of 9-bit index (3 radix-8 stages)
__device__ __forceinline__ int drev(int s) {
    return ((s & 7) << 6) | (s & 56) | (s >> 6);
}
// bank swizzle on float2 element index
__device__ __forceinline__ int fsw(int a) { return a + (a >> 3); }

__device__ __forceinline__ float2 cmul(float2 a, float2 b) {
    return make_float2(a.x*b.x - a.y*b.y, a.x*b.y + a.y*b.x);
}
#define C_ADD(a,b) make_float2((a).x+(b).x, (a).y+(b).y)
#define C_SUB(a,b) make_float2((a).x-(b).x, (a).y-(b).y)
#define C_NI(a)    make_float2((a).y, -(a).x)   // * (-i)

// radix-8 DIF butterfly, negative exponent
__device__ __forceinline__ void bfly8(float2 x[8]) {
    const float R = 0.70710678118654752440f;
    float2 t0=C_ADD(x[0],x[4]), t4=C_SUB(x[0],x[4]);
    float2 t1=C_ADD(x[1],x[5]), t5=C_SUB(x[1],x[5]);
    float2 t2=C_ADD(x[2],x[6]), t6=C_SUB(x[2],x[6]);
    float2 t3=C_ADD(x[3],x[7]), t7=C_SUB(x[3],x[7]);
    float2 u0=C_ADD(t0,t2), u2=C_SUB(t0,t2);
    float2 u1=C_ADD(t1,t3), u3=C_SUB(t1,t3);
    x[0]=C_ADD(u0,u1); x[4]=C_SUB(u0,u1);
    { float2 n3 = C_NI(u3); x[2]=C_ADD(u2,n3); x[6]=C_SUB(u2,n3); }
    float2 s1 = make_float2(R*(t5.x + t5.y), R*(t5.y - t5.x));   // * (R - iR)
    float2 s2 = C_NI(t6);
    float2 s3 = make_float2(R*(t7.y - t7.x), -R*(t7.x + t7.y));  // * (-R - iR)
    float2 v0=C_ADD(t4,s2), v2=C_SUB(t4,s2);
    float2 v1=C_ADD(s1,s3), v3=C_SUB(s1,s3);
    x[1]=C_ADD(v0,v1); x[5]=C_SUB(v0,v1);
    { float2 n3 = C_NI(v3); x[3]=C_ADD(v2,n3); x[7]=C_SUB(v2,n3); }
}

// x[j] *= w^j, w = exp(i*ang); chain depth 3 for ILP
__device__ __forceinline__ void twiddle7(float2* x, float ang) {
    const float sn = __sinf(ang), cs = __cosf(ang);
    const float2 w1 = make_float2(cs, sn);
    const float2 w2 = cmul(w1, w1);
    const float2 w3 = cmul(w2, w1);
    const float2 w4 = cmul(w2, w2);
    const float2 w5 = cmul(w2, w3);
    const float2 w6 = cmul(w3, w3);
    const float2 w7 = cmul(w3, w4);
    x[1]=cmul(x[1],w1); x[2]=cmul(x[2],w2); x[3]=cmul(x[3],w3);
    x[4]=cmul(x[4],w4); x[5]=cmul(x[5],w5); x[6]=cmul(x[6],w6);
    x[7]=cmul(x[7],w7);
}

// ---------------------------------------------------------------------------
// Pass A: one block per 4 row-pairs (8 image rows). Pack rows (2s,2s+1) as
// a+ib (float2 LDS), radix-8 512-pt DIF FFT, Hermitian unpack, LDS plane
// transpose, coalesced [y][kx] global writes. (Unchanged from R5: ~72% HBM.)
// ---------------------------------------------------------------------------
__global__ __launch_bounds__(256) void rowfft_kernel(
    const float* __restrict__ pred, const float* __restrict__ targ,
    float2* __restrict__ out, int img_base)
{
    __shared__ float2 sd[2320];        // 4*580 FFT slots; reused as 8*290 planes
    const int t = threadIdx.x;

    const int pb = blockIdx.x;         // rows pb*8 .. pb*8+7
    const int li = blockIdx.y;
    const int g  = img_base + li;
    const float* img = (g < NIMG_PER) ? (pred + (size_t)g * IMG)
                                      : (targ + (size_t)(g - NIMG_PER) * IMG);
    const float4* src4 = (const float4*)(img + (size_t)(pb*8) * WW);

    #pragma unroll
    for (int it = 0; it < 2; ++it) {
        const int id = it*256 + t;     // 0..511 = s*128 + x4
        const int s  = id >> 7;
        const int x4 = id & 127;
        const float4 va = src4[(2*s)   * 128 + x4];
        const float4 vb = src4[(2*s+1) * 128 + x4];
        float2* p = sd + s*SLOT + (4*x4 + (x4 >> 1));   // fsw(4*x4)
        p[0] = make_float2(va.x, vb.x);
        p[1] = make_float2(va.y, vb.y);
        p[2] = make_float2(va.z, vb.z);
        p[3] = make_float2(va.w, vb.w);
    }
    __syncthreads();

    const int i = t & 63;
    float2* p = sd + (t >> 6) * SLOT;
    float2 x[8];

    // stage 1: stride 64
    #pragma unroll
    for (int j = 0; j < 8; ++j) x[j] = p[fsw(i + 64*j)];
    bfly8(x);
    twiddle7(x, -0.012271846303085130f * (float)i);       // -2pi/512 * i
    #pragma unroll
    for (int j = 0; j < 8; ++j) p[fsw(i + 64*j)] = x[j];
    __syncthreads();

    // stage 2: groups of 64
    const int grp = i >> 3, i2 = i & 7;
    #pragma unroll
    for (int j = 0; j < 8; ++j) x[j] = p[fsw(64*grp + i2 + 8*j)];
    bfly8(x);
    twiddle7(x, -0.098174770424681038f * (float)i2);      // -2pi/64 * i2
    #pragma unroll
    for (int j = 0; j < 8; ++j) p[fsw(64*grp + i2 + 8*j)] = x[j];
    __syncthreads();

    // stage 3: contiguous 8
    #pragma unroll
    for (int j = 0; j < 8; ++j) x[j] = p[fsw(8*i + j)];
    bfly8(x);
    #pragma unroll
    for (int j = 0; j < 8; ++j) p[fsw(8*i + j)] = x[j];
    __syncthreads();

    // Hermitian unpack (see R5 comments for lane->k mapping)
    const int w_ = t >> 6;
    const int k  = (w_ > 0) ? (((t & 7) << 6) | (t & 56) | w_)
                            : ((t < 32) ? (8*t + 4) : (8*(t - 32)));
    const int kk = (k <= 256) ? k : (512 - k);
    const int a1 = fsw(drev(kk));
    const int a2 = fsw(drev((512 - kk) & 511));
    const int a3 = fsw(drev(256));

    float2 A[4], Bv[4], Z[4];
    #pragma unroll
    for (int s = 0; s < 4; ++s) {
        const float2 P = sd[s*SLOT + a1];
        const float2 Q = sd[s*SLOT + a2];
        A[s]  = make_float2(0.5f*(P.x + Q.x), 0.5f*(P.y - Q.y));
        Bv[s] = make_float2(0.5f*(P.y + Q.y), 0.5f*(Q.x - P.x));
        Z[s]  = sd[s*SLOT + a3];
    }
    __syncthreads();

    {
        const int fb = fsw(kk);
        #pragma unroll
        for (int s = 0; s < 4; ++s) {
            sd[(2*s+0)*290 + fb] = A[s];
            sd[(2*s+1)*290 + fb] = Bv[s];
        }
    }
    if (t == 0) {
        const int fb = fsw(256);
        #pragma unroll
        for (int s = 0; s < 4; ++s) {
            sd[(2*s+0)*290 + fb] = make_float2(Z[s].x, 0.0f);
            sd[(2*s+1)*290 + fb] = make_float2(Z[s].y, 0.0f);
        }
    }
    __syncthreads();

    float2* dst = out + (size_t)li * IMGC + (size_t)(pb*8) * CSTR;
    #pragma unroll
    for (int r = 0; r < 8; ++r) {
        dst[(size_t)r * CSTR + t] = sd[r*290 + fsw(t)];
        if (t < 8) {
            float2 v = make_float2(0.0f, 0.0f);
            if (t == 0) v = sd[r*290 + fsw(256)];
            dst[(size_t)r * CSTR + 256 + t] = v;
        }
    }
}

// ---------------------------------------------------------------------------
// Pass B: one block per (image, 8-column tile). 8 radix-8 column FFTs; stage 3
// writes back to LDS; binning phase: each thread owns a 16-consecutive-ky run
// of ONE column -> register run-accumulation, LDS atomic only on bin CHANGE.
// Block result -> private global slice (no global atomics).
// ---------------------------------------------------------------------------
__global__ __launch_bounds__(256) void colfft_kernel(
    const float2* __restrict__ in, float* __restrict__ bins2, int img_base)
{
    __shared__ float2 sd[8*SLOT];
    __shared__ float  bs[4*257];
    const int t = threadIdx.x;
    for (int id = t; id < 4*257; id += 256) bs[id] = 0.0f;

    const int li = blockIdx.y;
    const int x0 = blockIdx.x * 8;
    const float2* src = in + (size_t)li * IMGC;

    #pragma unroll
    for (int it = 0; it < 16; ++it) {
        const int id = it*256 + t;        // 0..4095
        const int y  = id >> 3;
        const int cl = id & 7;
        sd[cl*SLOT + fsw(y)] = src[(size_t)y * CSTR + (x0 + cl)];
    }
    __syncthreads();

    const int i  = t & 63;
    const int c0 = t >> 6;                // slots c0 and c0+4
    float2 x[2][8];

    // ---- stage 1
    #pragma unroll
    for (int sl = 0; sl < 2; ++sl) {
        float2* p = sd + (c0 + 4*sl)*SLOT;
        #pragma unroll
        for (int j = 0; j < 8; ++j) x[sl][j] = p[fsw(i + 64*j)];
        bfly8(x[sl]);
    }
    {
        const float ang = -0.012271846303085130f * (float)i;
        const float sn = __sinf(ang), cs = __cosf(ang);
        const float2 w1 = make_float2(cs, sn);
        const float2 w2 = cmul(w1,w1), w3 = cmul(w2,w1), w4 = cmul(w2,w2);
        const float2 w5 = cmul(w2,w3), w6 = cmul(w3,w3), w7 = cmul(w3,w4);
        #pragma unroll
        for (int sl = 0; sl < 2; ++sl) {
            x[sl][1]=cmul(x[sl][1],w1); x[sl][2]=cmul(x[sl][2],w2);
            x[sl][3]=cmul(x[sl][3],w3); x[sl][4]=cmul(x[sl][4],w4);
            x[sl][5]=cmul(x[sl][5],w5); x[sl][6]=cmul(x[sl][6],w6);
            x[sl][7]=cmul(x[sl][7],w7);
        }
    }
    #pragma unroll
    for (int sl = 0; sl < 2; ++sl) {
        float2* p = sd + (c0 + 4*sl)*SLOT;
        #pragma unroll
        for (int j = 0; j < 8; ++j) p[fsw(i + 64*j)] = x[sl][j];
    }
    __syncthreads();

    // ---- stage 2
    const int grp = i >> 3, i2 = i & 7;
    #pragma unroll
    for (int sl = 0; sl < 2; ++sl) {
        float2* p = sd + (c0 + 4*sl)*SLOT;
        #pragma unroll
        for (int j = 0; j < 8; ++j) x[sl][j] = p[fsw(64*grp + i2 + 8*j)];
        bfly8(x[sl]);
    }
    {
        const float ang = -0.098174770424681038f * (float)i2;
        const float sn = __sinf(ang), cs = __cosf(ang);
        const float2 w1 = make_float2(cs, sn);
        const float2 w2 = cmul(w1,w1), w3 = cmul(w2,w1), w4 = cmul(w2,w2);
        const float2 w5 = cmul(w2,w3), w6 = cmul(w3,w3), w7 = cmul(w3,w4);
        #pragma unroll
        for (int sl = 0; sl < 2; ++sl) {
            x[sl][1]=cmul(x[sl][1],w1); x[sl][2]=cmul(x[sl][2],w2);
            x[sl][3]=cmul(x[sl][3],w3); x[sl][4]=cmul(x[sl][4],w4);
            x[sl][5]=cmul(x[sl][5],w5); x[sl][6]=cmul(x[sl][6],w6);
            x[sl][7]=cmul(x[sl][7],w7);
        }
    }
    #pragma unroll
    for (int sl = 0; sl < 2; ++sl) {
        float2* p = sd + (c0 + 4*sl)*SLOT;
        #pragma unroll
        for (int j = 0; j < 8; ++j) p[fsw(64*grp + i2 + 8*j)] = x[sl][j];
    }
    __syncthreads();

    // ---- stage 3: compute and write final F back to LDS
    #pragma unroll
    for (int sl = 0; sl < 2; ++sl) {
        float2* p = sd + (c0 + 4*sl)*SLOT;
        float2 y8[8];
        #pragma unroll
        for (int j = 0; j < 8; ++j) y8[j] = p[fsw(8*i + j)];
        bfly8(y8);
        #pragma unroll
        for (int j = 0; j < 8; ++j) p[fsw(8*i + j)] = y8[j];
    }
    __syncthreads();

    // ---- binning: thread owns ky = 16h .. 16h+15 of column cl2.
    // Bin index is piecewise-constant along consecutive ky -> accumulate runs
    // in registers, LDS atomic only on bin change. Colliding flush lanes are
    // lane-consecutive -> replica by (t&3).
    {
        const int cl2 = t & 7;
        const int h   = t >> 3;            // 0..31
        const int kx  = x0 + cl2;
        const bool valid = (kx <= 256);
        const float scale = (kx == 0 || kx == 256) ? 0.5f : 1.0f;
        const int dxsq = (kx - 256) * (kx - 256);
        const int rep  = (t & 3) * 257;

        float acc = 0.0f;
        int prevb = 1000;
        #pragma unroll
        for (int j = 0; j < 16; ++j) {
            const int q = 64*(j & 7) + 8*((2*h + (j >> 3)) & 7) + (h >> 2); // drev(16h+j)
            const float2 v = sd[cl2*SLOT + fsw(q)];
            const float val = __logf(v.x*v.x + v.y*v.y + EPSV) * scale;
            const int dy = 16*h + j - 256;
            const int b  = (int)sqrtf((float)(dy*dy + dxsq));
            if (b != prevb) {
                if (prevb < NBIN && valid) atomicAdd(&bs[rep + prevb], acc);
                prevb = b; acc = val;
            } else {
                acc += val;
            }
        }
        if (prevb < NBIN && valid) atomicAdd(&bs[rep + prevb], acc);
    }
    __syncthreads();

    // weight 2 for interior kx folded here (kx 0/256 pre-scaled by 0.5)
    const float v = 2.0f * (bs[t] + bs[257 + t] + bs[514 + t] + bs[771 + t]);
    bins2[((size_t)blockIdx.x * NIMG + (img_base + li)) * NBIN + t] = v;
}

// ---------------------------------------------------------------------------
// Reduce the 33 per-tile slices into bins[img][bin] (plain stores).
// ---------------------------------------------------------------------------
__global__ __launch_bounds__(256) void reduce_kernel(
    const float* __restrict__ bins2, float* __restrict__ bins)
{
    const int li = blockIdx.x;
    const int t  = threadIdx.x;
    float s = 0.0f;
    #pragma unroll
    for (int tile = 0; tile < NTILE; ++tile)
        s += bins2[((size_t)tile * NIMG + li) * NBIN + t];
    bins[(size_t)li * NBIN + t] = s;
}

// ---------------------------------------------------------------------------
// Bin counts over the full 512x512 grid (image-independent).
// ---------------------------------------------------------------------------
__global__ __launch_bounds__(256) void counts_kernel(float* __restrict__ cnt)
{
    __shared__ float c[NBIN];
    const int t = threadIdx.x;
    c[t] = 0.0f;
    __syncthreads();

    const int base = blockIdx.x * 4096;
    #pragma unroll
    for (int i = 0; i < 16; ++i) {
        const int id = base + i * 256 + t;
        const int y = id >> 9, xx = id & 511;
        const int dy = y - 256, dx = xx - 256;
        const int b  = (int)sqrtf((float)(dy*dy + dx*dx));
        if (b < NBIN) atomicAdd(&c[b], 1.0f);
    }
    __syncthreads();
    if (c[t] != 0.0f) atomicAdd(&cnt[t], c[t]);
}

// ---------------------------------------------------------------------------
// Finalize: mean over (pair, bin) of |sum_p - sum_t| / cnt.
// ---------------------------------------------------------------------------
__global__ __launch_bounds__(256) void finalize_kernel(
    const float* __restrict__ bins, const float* __restrict__ cnt,
    float* __restrict__ out)
{
    __shared__ float red[256];
    const int t = threadIdx.x;

    float acc = 0.0f;
    for (int id = t; id < NIMG_PER * NBIN; id += 256) {
        const int i = id >> 8;
        const int r = id & 255;
        const float d = fabsf(bins[(size_t)i * NBIN + r]
                            - bins[(size_t)(NIMG_PER + i) * NBIN + r]);
        acc += d / cnt[r];
    }
    red[t] = acc;
    __syncthreads();
    for (int w = 128; w > 0; w >>= 1) {
        if (t < w) red[t] += red[t + w];
        __syncthreads();
    }
    if (t == 0) out[0] = red[0] / (float)(NIMG_PER * NBIN);
}

// ---------------------------------------------------------------------------
extern "C" void kernel_launch(void* const* d_in, const int* in_sizes, int n_in,
                              void* d_out, int out_size, void* d_ws, size_t ws_size,
                              hipStream_t stream)
{
    const float* pred = (const float*)d_in[0];
    const float* targ = (const float*)d_in[1];
    float* out = (float*)d_out;

    char* ws = (char*)d_ws;
    float* cnt   = (float*)ws;                                  // 256
    float* bins  = cnt + NBIN;                                  // 192*256
    float* bins2 = bins + (size_t)NIMG * NBIN;                  // 33*192*256
    const size_t fixed_f = NBIN + (size_t)NIMG*NBIN + (size_t)NTILE*NIMG*NBIN;
    const size_t off = (fixed_f*sizeof(float) + 255) & ~(size_t)255;
    float2* cbuf = (float2*)(ws + off);

    const size_t per_img = (size_t)IMGC * sizeof(float2);       // ~1.06 MiB
    size_t avail = (ws_size > off) ? (ws_size - off) : 0;
    int chunk = (int)(avail / per_img);
    if (chunk > NIMG) chunk = NIMG;
    if (chunk < 1) chunk = 1;

    hipMemsetAsync(cnt, 0, NBIN * sizeof(float), stream);
    counts_kernel<<<dim3(64), dim3(256), 0, stream>>>(cnt);

    for (int base = 0; base < NIMG; base += chunk) {
        const int n = (NIMG - base < chunk) ? (NIMG - base) : chunk;
        dim3 gA(HH / 8, n), gB(NTILE, n), blk(256);
        rowfft_kernel<<<gA, blk, 0, stream>>>(pred, targ, cbuf, base);
        colfft_kernel<<<gB, blk, 0, stream>>>(cbuf, bins2, base);
    }

    reduce_kernel<<<dim3(NIMG), dim3(256), 0, stream>>>(bins2, bins);
    finalize_kernel<<<dim3(1), dim3(256), 0, stream>>>(bins, cnt, out);
}